// Round 5
// baseline (459.730 us; speedup 1.0000x reference)
//
#include <hip/hip_runtime.h>
#include <cstddef>
#include <cstdint>

#define BB 4
#define LL 2048
#define DD 1024
#define HH 16
#define DHD 64
#define QSCALE 0.18033688f  // 0.125 * log2(e): softmax in base-2 domain

typedef short s16x8 __attribute__((ext_vector_type(8)));
typedef short s16x4 __attribute__((ext_vector_type(4)));
typedef float f32x4 __attribute__((ext_vector_type(4)));
typedef unsigned int u32;
typedef u32 u32x2 __attribute__((ext_vector_type(2)));

__device__ __forceinline__ short f2bf(float f) {
  union { float f; u32 u; } x; x.f = f;
  u32 r = x.u + 0x7FFFu + ((x.u >> 16) & 1u);
  return (short)(r >> 16);
}
// pack two f32 -> two bf16 (round-half-up) in one v_perm
__device__ __forceinline__ u32 pack2bf(float a, float b) {
  union { float f; u32 u; } x, y; x.f = a; y.f = b;
  return __builtin_amdgcn_perm(y.u + 0x8000u, x.u + 0x8000u, 0x07060302u);
}
__device__ __forceinline__ void gl2lds16(const short* g, short* l) {
  __builtin_amdgcn_global_load_lds(
      (const __attribute__((address_space(1))) unsigned int*)g,
      (__attribute__((address_space(3))) unsigned int*)l, 16, 0, 0);
}

// ---------------- fused casts ----------------
__global__ __launch_bounds__(256) void cast_x_kernel(const float* __restrict__ q,
                                                     const float* __restrict__ k,
                                                     const float* __restrict__ v,
                                                     short* __restrict__ qb,
                                                     short* __restrict__ kb,
                                                     short* __restrict__ vb) {
  const float* s; short* d;
  if (blockIdx.y == 0) { s = q; d = qb; }
  else if (blockIdx.y == 1) { s = k; d = kb; }
  else { s = v; d = vb; }
  int i = blockIdx.x * 256 + threadIdx.x;
  float4 x = ((const float4*)s)[i];
  s16x4 o; o.x = f2bf(x.x); o.y = f2bf(x.y); o.z = f2bf(x.z); o.w = f2bf(x.w);
  ((s16x4*)d)[i] = o;
}

__global__ __launch_bounds__(256) void cast_w_kernel(const float* __restrict__ Wq,
                                                     const float* __restrict__ Wk,
                                                     const float* __restrict__ Wv,
                                                     const float* __restrict__ Wo,
                                                     short* __restrict__ Wqb,
                                                     short* __restrict__ Wkb,
                                                     short* __restrict__ Wvb,
                                                     short* __restrict__ Wob) {
  const float* s; short* d; float sc = 1.0f;
  if (blockIdx.y == 0) { s = Wq; d = Wqb; sc = QSCALE; }
  else if (blockIdx.y == 1) { s = Wk; d = Wkb; }
  else if (blockIdx.y == 2) { s = Wv; d = Wvb; }
  else { s = Wo; d = Wob; }
  int i = blockIdx.x * 256 + threadIdx.x;
  float4 x = ((const float4*)s)[i];
  s16x4 o; o.x = f2bf(x.x * sc); o.y = f2bf(x.y * sc); o.z = f2bf(x.z * sc); o.w = f2bf(x.w * sc);
  ((s16x4*)d)[i] = o;
}

__global__ __launch_bounds__(256) void mask_kernel(const int* __restrict__ mask,
                                                   float* __restrict__ maskadd) {
  int i = blockIdx.x * 256 + threadIdx.x;  // int4 each
  int4 m = ((const int4*)mask)[i];
  f32x4 o;
  o[0] = (m.x == 1) ? 0.0f : -30000.0f;
  o[1] = (m.y == 1) ? 0.0f : -30000.0f;
  o[2] = (m.z == 1) ? 0.0f : -30000.0f;
  o[3] = (m.w == 1) ? 0.0f : -30000.0f;
  ((f32x4*)maskadd)[i] = o;
}

// ---------------- shared GEMM core (128x128 tile, bt layout) ----------------
// A staged via global_load_lds (XOR-swizzled LDS); B fragments loaded DIRECTLY
// global->VGPR (L2-resident operand), issued before the A-staging barriers so
// their latency hides under the vmcnt drain. Halves LDS traffic vs dual-stage.
__device__ __forceinline__ void gemm_core(const short* __restrict__ A, const short* __restrict__ B,
                                          int K, int bm, int bn, short* As,
                                          f32x4 (&acc)[4][4]) {
  const int tid = threadIdx.x;
  const int lane = tid & 63, wave = tid >> 6;
  const int wv = __builtin_amdgcn_readfirstlane(wave);
  const int quad = lane >> 4, l16 = lane & 15;
  const int wm = (wave >> 1) * 64, wn = (wave & 1) * 64;
  const short* ap[4]; short* la[4];
#pragma unroll
  for (int t = 0; t < 4; ++t) {
    int s = wv * 256 + t * 64 + lane;
    int r = s >> 3, gl = (s & 7) ^ (r & 7);
    ap[t] = A + (size_t)(bm + r) * K + gl * 8;
    la[t] = &As[(wv * 256 + t * 64) * 8];
  }
  const short* Bl = B + (size_t)(bn + wn + l16) * K + quad * 8;
  const int sw0 = (quad ^ (l16 & 7)) * 8;
  const int sw1 = ((4 + quad) ^ (l16 & 7)) * 8;
  for (int kk = 0; kk < K; kk += 64) {
    // B fragments for this K-slab: direct global (L2-hot), overlap barrier drain
    s16x8 bf[2][4];
#pragma unroll
    for (int c = 0; c < 2; ++c)
#pragma unroll
      for (int t = 0; t < 4; ++t)
        bf[c][t] = *(const s16x8*)&Bl[(size_t)(t * 16) * K + kk + c * 32];
    __syncthreads();
#pragma unroll
    for (int t = 0; t < 4; ++t) gl2lds16(ap[t] + kk, la[t]);
    __syncthreads();
#pragma unroll
    for (int c = 0; c < 2; ++c) {
      const int sw = c ? sw1 : sw0;
      s16x8 af[4];
#pragma unroll
      for (int t = 0; t < 4; ++t) af[t] = *(const s16x8*)&As[(wm + t * 16 + l16) * 64 + sw];
#pragma unroll
      for (int mt = 0; mt < 4; ++mt)
#pragma unroll
        for (int nt = 0; nt < 4; ++nt)
          acc[mt][nt] = __builtin_amdgcn_mfma_f32_16x16x32_bf16(af[mt], bf[c][nt], acc[mt][nt], 0, 0, 0);
    }
  }
}

// fused QKV projections; grid (8, 64, 3). z=0: Q, z=1: K (head-split out), z=2: V^T out.
__global__ __launch_bounds__(256) void qkv_gemm(const short* __restrict__ qb, const short* __restrict__ kb,
                                                const short* __restrict__ vb, const short* __restrict__ Wqb,
                                                const short* __restrict__ Wkb, const short* __restrict__ Wvb,
                                                short* __restrict__ Qh, short* __restrict__ Kh,
                                                short* __restrict__ VT) {
  __shared__ short As[128 * 64];
  const int z = blockIdx.z;
  const short *A, *B; short* C;
  if (z == 0) { A = qb; B = Wqb; C = Qh; }
  else if (z == 1) { A = kb; B = Wkb; C = Kh; }
  else { A = Wvb; B = vb; C = VT; }
  const int bm = (z == 2 ? blockIdx.x : (int)blockIdx.y) * 128;
  const int bn = (z == 2 ? (int)blockIdx.y : (int)blockIdx.x) * 128;
  f32x4 acc[4][4] = {};
  gemm_core(A, B, DD, bm, bn, As, acc);

  const int lane = threadIdx.x & 63, wave = threadIdx.x >> 6;
  const int quad = lane >> 4, l16 = lane & 15;
  const int wm = (wave >> 1) * 64, wn = (wave & 1) * 64;
#pragma unroll
  for (int mt = 0; mt < 4; ++mt)
#pragma unroll
    for (int nt = 0; nt < 4; ++nt)
#pragma unroll
      for (int i = 0; i < 4; ++i) {
        int m = bm + wm + mt * 16 + quad * 4 + i;
        int n = bn + wn + nt * 16 + l16;
        float val = acc[mt][nt][i];
        if (z < 2) {  // head-split [B,H,L,DH]
          int b = m >> 11, l = m & 2047;
          C[((size_t)(b * HH + (n >> 6)) << 17) + (size_t)l * DHD + (n & 63)] = f2bf(val);
        } else {      // V^T [B,H,DH,L]
          int b = n >> 11, l = n & 2047;
          C[((size_t)(b * DD + m) << 11) + l] = f2bf(val);
        }
      }
}

// output projection: fp32 out, grid (8, 64)
__global__ __launch_bounds__(256) void out_gemm(const short* __restrict__ A, const short* __restrict__ B,
                                                float* __restrict__ C) {
  __shared__ short As[128 * 64];
  const int bm = blockIdx.y * 128, bn = blockIdx.x * 128;
  f32x4 acc[4][4] = {};
  gemm_core(A, B, DD, bm, bn, As, acc);
  const int lane = threadIdx.x & 63, wave = threadIdx.x >> 6;
  const int quad = lane >> 4, l16 = lane & 15;
  const int wm = (wave >> 1) * 64, wn = (wave & 1) * 64;
#pragma unroll
  for (int mt = 0; mt < 4; ++mt)
#pragma unroll
    for (int nt = 0; nt < 4; ++nt)
#pragma unroll
      for (int i = 0; i < 4; ++i) {
        int m = bm + wm + mt * 16 + quad * 4 + i;
        int n = bn + wn + nt * 16 + l16;
        C[(size_t)m * DD + n] = acc[mt][nt][i];
      }
}

// ---------------- flash attention, S^T formulation, max-free base-2 softmax ----
// K fragments loaded DIRECTLY global->VGPR (K-tile is XCD-L2-resident thanks to
// grid (bh, qblk): all q-blocks of one head land on XCD bh%8). Only V and the
// P layout-transform go through LDS. grid: (B*H, L/128).
__global__ __launch_bounds__(256, 4) void attn_kernel(const short* __restrict__ Qh,
                                                      const short* __restrict__ Kh,
                                                      const short* __restrict__ VT,
                                                      const float* __restrict__ maskadd,
                                                      short* __restrict__ AO) {
  __shared__ short Vs[64 * 64];
  __shared__ short Pb[8 * 16 * 64];  // [wave][u][16 q-rows][64 s], XOR-swizzled
  const int tid  = threadIdx.x;
  const int lane = tid & 63, wave = tid >> 6;
  const int wv   = __builtin_amdgcn_readfirstlane(wave);
  const int quad = lane >> 4, l16 = lane & 15;
  const int a7 = l16 & 7, q1 = quad >> 1, qlo = quad & 1;
  const int bh = blockIdx.x, b = bh >> 4;
  const int q0 = blockIdx.y * 128;

  const float* mrow = maskadd + b * LL;
  const short* Qb = Qh + (size_t)bh * LL * DHD;
  const short* Kb = Kh + (size_t)bh * LL * DHD;
  const short* Vb = VT + (size_t)bh * DHD * LL;

  s16x8 qf[2][2];
#pragma unroll
  for (int u = 0; u < 2; ++u)
#pragma unroll
    for (int c = 0; c < 2; ++c)
      qf[u][c] = *(const s16x8*)&Qb[(size_t)(q0 + wv * 32 + u * 16 + l16) * DHD + c * 32 + quad * 8];

  // K per-lane base for direct A-operand loads
  const short* Kl = Kb + l16 * DHD + quad * 8;

  // V staging (global_load_lds), 2 insts per wave
  const short* vp[2]; short* lv[2];
#pragma unroll
  for (int t = 0; t < 2; ++t) {
    int s = wv * 128 + t * 64 + lane;
    int r = s >> 3, gl = (s & 7) ^ (r & 7);
    vp[t] = Vb + (size_t)r * LL + gl * 8;
    lv[t] = &Vs[(wv * 128 + t * 64) * 8];
  }
  const int sw0 = (quad ^ a7) * 8;
  const int sw1 = ((4 + quad) ^ a7) * 8;

  s16x8 vone;
#pragma unroll
  for (int j = 0; j < 8; ++j) vone[j] = (short)0x3F80;  // bf16 1.0

  f32x4 lsum[2] = {};
  f32x4 accO[2][4] = {};
  short* pb = &Pb[wave * 2048 + l16 * 64 + qlo * 4];

  for (int s0 = 0; s0 < LL; s0 += 64) {
    // K fragments: direct global (L2-hot), overlap the V-staging barrier drain
    s16x8 kf[4][2];
#pragma unroll
    for (int st = 0; st < 4; ++st)
#pragma unroll
      for (int c = 0; c < 2; ++c)
        kf[st][c] = *(const s16x8*)&Kl[(size_t)(s0 + st * 16) * DHD + c * 32];
    f32x4 mm[4];
#pragma unroll
    for (int st = 0; st < 4; ++st) mm[st] = *(const f32x4*)&mrow[s0 + st * 16 + quad * 4];

    __syncthreads();
#pragma unroll
    for (int t = 0; t < 2; ++t) gl2lds16(vp[t] + s0, lv[t]);
    __syncthreads();

    f32x4 sc[2][4];
#pragma unroll
    for (int u = 0; u < 2; ++u)
#pragma unroll
      for (int st = 0; st < 4; ++st) {
        sc[u][st] = __builtin_amdgcn_mfma_f32_16x16x32_bf16(kf[st][0], qf[u][0], mm[st], 0, 0, 0);
        sc[u][st] = __builtin_amdgcn_mfma_f32_16x16x32_bf16(kf[st][1], qf[u][1], sc[u][st], 0, 0, 0);
      }

    // P = exp2(score); pack to bf16; write to Pb (A-operand layout transform)
#pragma unroll
    for (int u = 0; u < 2; ++u)
#pragma unroll
      for (int st = 0; st < 4; ++st) {
        float p0 = __builtin_amdgcn_exp2f(sc[u][st][0]);
        float p1 = __builtin_amdgcn_exp2f(sc[u][st][1]);
        float p2 = __builtin_amdgcn_exp2f(sc[u][st][2]);
        float p3 = __builtin_amdgcn_exp2f(sc[u][st][3]);
        u32x2 w; w[0] = pack2bf(p0, p1); w[1] = pack2bf(p2, p3);
        *(u32x2*)(pb + u * 1024 + (((st * 2 + q1) ^ a7) << 3)) = w;
      }

    s16x8 pf[2][2];
#pragma unroll
    for (int u = 0; u < 2; ++u)
#pragma unroll
      for (int c = 0; c < 2; ++c)
        pf[u][c] = *(const s16x8*)&Pb[(wave * 2 + u) * 1024 + l16 * 64 + (((c * 4 + quad) ^ a7) << 3)];
#pragma unroll
    for (int u = 0; u < 2; ++u) {
      lsum[u] = __builtin_amdgcn_mfma_f32_16x16x32_bf16(pf[u][0], vone, lsum[u], 0, 0, 0);
      lsum[u] = __builtin_amdgcn_mfma_f32_16x16x32_bf16(pf[u][1], vone, lsum[u], 0, 0, 0);
    }
#pragma unroll
    for (int dt = 0; dt < 4; ++dt) {
      s16x8 vf0 = *(const s16x8*)&Vs[(dt * 16 + l16) * 64 + sw0];
      s16x8 vf1 = *(const s16x8*)&Vs[(dt * 16 + l16) * 64 + sw1];
#pragma unroll
      for (int u = 0; u < 2; ++u) {
        accO[u][dt] = __builtin_amdgcn_mfma_f32_16x16x32_bf16(pf[u][0], vf0, accO[u][dt], 0, 0, 0);
        accO[u][dt] = __builtin_amdgcn_mfma_f32_16x16x32_bf16(pf[u][1], vf1, accO[u][dt], 0, 0, 0);
      }
    }
  }

  short* AOb = AO + (size_t)b * LL * DD + (size_t)(bh & 15) * DHD;
#pragma unroll
  for (int u = 0; u < 2; ++u) {
    f32x4 rl;
#pragma unroll
    for (int i = 0; i < 4; ++i) rl[i] = __builtin_amdgcn_rcpf(lsum[u][i]);
#pragma unroll
    for (int dt = 0; dt < 4; ++dt)
#pragma unroll
      for (int i = 0; i < 4; ++i) {
        int qr = q0 + wv * 32 + u * 16 + quad * 4 + i;
        AOb[(size_t)qr * DD + dt * 16 + l16] = f2bf(accO[u][dt][i] * rl[i]);
      }
  }
}

extern "C" void kernel_launch(void* const* d_in, const int* in_sizes, int n_in,
                              void* d_out, int out_size, void* d_ws, size_t ws_size,
                              hipStream_t stream) {
  const float* q   = (const float*)d_in[0];
  const float* k   = (const float*)d_in[1];
  const float* v   = (const float*)d_in[2];
  const int*  mask = (const int*)d_in[3];
  const float* Wq  = (const float*)d_in[4];
  const float* Wk  = (const float*)d_in[5];
  const float* Wv  = (const float*)d_in[6];
  const float* Wo  = (const float*)d_in[7];

  const size_t SX = (size_t)BB * LL * DD;  // 8,388,608
  const size_t SW = (size_t)DD * DD;       // 1,048,576
  short* w = (short*)d_ws;
  short* qb  = w;        short* kb  = qb + SX;  short* vb  = kb + SX;
  short* Wqb = vb + SX;  short* Wkb = Wqb + SW; short* Wvb = Wkb + SW; short* Wob = Wvb + SW;
  short* Qh  = Wob + SW; short* Kh  = Qh + SX;  short* VT  = Kh + SX;
  float* maskadd = (float*)(VT + SX);
  short* AO = qb;  // qb dead after QKV projections

  cast_x_kernel<<<dim3((unsigned)(SX / 4 / 256), 3), 256, 0, stream>>>(q, k, v, qb, kb, vb);
  cast_w_kernel<<<dim3((unsigned)(SW / 4 / 256), 4), 256, 0, stream>>>(Wq, Wk, Wv, Wo, Wqb, Wkb, Wvb, Wob);
  mask_kernel<<<BB * LL / 4 / 256, 256, 0, stream>>>(mask, maskadd);

  qkv_gemm<<<dim3(8, 64, 3), 256, 0, stream>>>(qb, kb, vb, Wqb, Wkb, Wvb, Qh, Kh, VT);
  attn_kernel<<<dim3(BB * HH, LL / 128), 256, 0, stream>>>(Qh, Kh, VT, maskadd, AO);
  out_gemm<<<dim3(8, 64), 256, 0, stream>>>(AO, Wob, (float*)d_out);
}

// Round 6
// 386.499 us; speedup vs baseline: 1.1895x; 1.1895x over previous
//
#include <hip/hip_runtime.h>
#include <cstddef>
#include <cstdint>

#define BB 4
#define LL 2048
#define DD 1024
#define HH 16
#define DHD 64
#define QSCALE 0.18033688f  // 0.125 * log2(e): softmax in base-2 domain

typedef short s16x8 __attribute__((ext_vector_type(8)));
typedef short s16x4 __attribute__((ext_vector_type(4)));
typedef float f32x4 __attribute__((ext_vector_type(4)));
typedef unsigned int u32;
typedef u32 u32x2 __attribute__((ext_vector_type(2)));

__device__ __forceinline__ short f2bf(float f) {
  union { float f; u32 u; } x; x.f = f;
  u32 r = x.u + 0x7FFFu + ((x.u >> 16) & 1u);
  return (short)(r >> 16);
}
// pack two f32 -> two bf16 (round-half-up) in one v_perm
__device__ __forceinline__ u32 pack2bf(float a, float b) {
  union { float f; u32 u; } x, y; x.f = a; y.f = b;
  return __builtin_amdgcn_perm(y.u + 0x8000u, x.u + 0x8000u, 0x07060302u);
}
__device__ __forceinline__ void gl2lds16(const short* g, short* l) {
  __builtin_amdgcn_global_load_lds(
      (const __attribute__((address_space(1))) unsigned int*)g,
      (__attribute__((address_space(3))) unsigned int*)l, 16, 0, 0);
}

// ---------------- fused casts ----------------
__global__ __launch_bounds__(256) void cast_x_kernel(const float* __restrict__ q,
                                                     const float* __restrict__ k,
                                                     const float* __restrict__ v,
                                                     short* __restrict__ qb,
                                                     short* __restrict__ kb,
                                                     short* __restrict__ vb) {
  const float* s; short* d;
  if (blockIdx.y == 0) { s = q; d = qb; }
  else if (blockIdx.y == 1) { s = k; d = kb; }
  else { s = v; d = vb; }
  int i = blockIdx.x * 256 + threadIdx.x;
  float4 x = ((const float4*)s)[i];
  s16x4 o; o.x = f2bf(x.x); o.y = f2bf(x.y); o.z = f2bf(x.z); o.w = f2bf(x.w);
  ((s16x4*)d)[i] = o;
}

__global__ __launch_bounds__(256) void cast_w_kernel(const float* __restrict__ Wq,
                                                     const float* __restrict__ Wk,
                                                     const float* __restrict__ Wv,
                                                     const float* __restrict__ Wo,
                                                     short* __restrict__ Wqb,
                                                     short* __restrict__ Wkb,
                                                     short* __restrict__ Wvb,
                                                     short* __restrict__ Wob) {
  const float* s; short* d; float sc = 1.0f;
  if (blockIdx.y == 0) { s = Wq; d = Wqb; sc = QSCALE; }
  else if (blockIdx.y == 1) { s = Wk; d = Wkb; }
  else if (blockIdx.y == 2) { s = Wv; d = Wvb; }
  else { s = Wo; d = Wob; }
  int i = blockIdx.x * 256 + threadIdx.x;
  float4 x = ((const float4*)s)[i];
  s16x4 o; o.x = f2bf(x.x * sc); o.y = f2bf(x.y * sc); o.z = f2bf(x.z * sc); o.w = f2bf(x.w * sc);
  ((s16x4*)d)[i] = o;
}

__global__ __launch_bounds__(256) void mask_kernel(const int* __restrict__ mask,
                                                   float* __restrict__ maskadd) {
  int i = blockIdx.x * 256 + threadIdx.x;  // int4 each
  int4 m = ((const int4*)mask)[i];
  f32x4 o;
  o[0] = (m.x == 1) ? 0.0f : -30000.0f;
  o[1] = (m.y == 1) ? 0.0f : -30000.0f;
  o[2] = (m.z == 1) ? 0.0f : -30000.0f;
  o[3] = (m.w == 1) ? 0.0f : -30000.0f;
  ((f32x4*)maskadd)[i] = o;
}

// ---------------- pipelined GEMM core (128x128 tile, bt layout) --------------
// Single barrier per K-slab: A double-buffered in LDS via global_load_lds;
// B prefetched global->VGPR ONE SLAB AHEAD so the barrier's vmcnt(0) drain
// covers loads issued a full compute-phase earlier (R5's same-iter direct
// loads exposed raw L2 latency every iteration). LDS traffic halves vs
// dual-staging -> LDS pipe no longer the ceiling.
__device__ __forceinline__ void gemm_core(const short* __restrict__ A, const short* __restrict__ B,
                                          int K, int bm, int bn, short* As,
                                          f32x4 (&acc)[4][4]) {
  const int tid = threadIdx.x;
  const int lane = tid & 63, wave = tid >> 6;
  const int wv = __builtin_amdgcn_readfirstlane(wave);
  const int quad = lane >> 4, l16 = lane & 15;
  const int wm = (wave >> 1) * 64, wn = (wave & 1) * 64;
  const short* ap[4]; int laoff[4];
#pragma unroll
  for (int t = 0; t < 4; ++t) {
    int s = wv * 256 + t * 64 + lane;
    int r = s >> 3, gl = (s & 7) ^ (r & 7);
    ap[t] = A + (size_t)(bm + r) * K + gl * 8;
    laoff[t] = (wv * 256 + t * 64) * 8;
  }
  const short* Bl = B + (size_t)(bn + wn + l16) * K + quad * 8;
  const int sw0 = (quad ^ (l16 & 7)) * 8;
  const int sw1 = ((4 + quad) ^ (l16 & 7)) * 8;

  // prologue: stage A slab 0 into buf0, prefetch B slab 0
#pragma unroll
  for (int t = 0; t < 4; ++t) gl2lds16(ap[t], &As[laoff[t]]);
  s16x8 bcur[2][4];
#pragma unroll
  for (int c = 0; c < 2; ++c)
#pragma unroll
    for (int t = 0; t < 4; ++t)
      bcur[c][t] = *(const s16x8*)&Bl[(size_t)(t * 16) * K + c * 32];

  for (int kk = 0; kk < K; kk += 64) {
    const int cur = (kk >> 6) & 1;
    short* Ac = As + cur * (128 * 64);
    __syncthreads();  // drains last iter's gl2lds + B prefetch (vmcnt(0))
    s16x8 bnxt[2][4];
    if (kk + 64 < K) {
#pragma unroll
      for (int t = 0; t < 4; ++t)
        gl2lds16(ap[t] + kk + 64, &As[(cur ^ 1) * (128 * 64) + laoff[t]]);
#pragma unroll
      for (int c = 0; c < 2; ++c)
#pragma unroll
        for (int t = 0; t < 4; ++t)
          bnxt[c][t] = *(const s16x8*)&Bl[(size_t)(t * 16) * K + kk + 64 + c * 32];
    }
#pragma unroll
    for (int c = 0; c < 2; ++c) {
      const int sw = c ? sw1 : sw0;
      s16x8 af[4];
#pragma unroll
      for (int t = 0; t < 4; ++t) af[t] = *(const s16x8*)&Ac[(wm + t * 16 + l16) * 64 + sw];
#pragma unroll
      for (int mt = 0; mt < 4; ++mt)
#pragma unroll
        for (int nt = 0; nt < 4; ++nt)
          acc[mt][nt] = __builtin_amdgcn_mfma_f32_16x16x32_bf16(af[mt], bcur[c][nt], acc[mt][nt], 0, 0, 0);
    }
#pragma unroll
    for (int c = 0; c < 2; ++c)
#pragma unroll
      for (int t = 0; t < 4; ++t) bcur[c][t] = bnxt[c][t];
  }
}

// fused QKV projections; grid (8, 64, 3). z=0: Q, z=1: K (head-split out), z=2: V^T out.
__global__ __launch_bounds__(256) void qkv_gemm(const short* __restrict__ qb, const short* __restrict__ kb,
                                                const short* __restrict__ vb, const short* __restrict__ Wqb,
                                                const short* __restrict__ Wkb, const short* __restrict__ Wvb,
                                                short* __restrict__ Qh, short* __restrict__ Kh,
                                                short* __restrict__ VT) {
  __shared__ short As[2 * 128 * 64];
  const int z = blockIdx.z;
  const short *A, *B; short* C;
  if (z == 0) { A = qb; B = Wqb; C = Qh; }
  else if (z == 1) { A = kb; B = Wkb; C = Kh; }
  else { A = Wvb; B = vb; C = VT; }
  const int bm = (z == 2 ? blockIdx.x : (int)blockIdx.y) * 128;
  const int bn = (z == 2 ? (int)blockIdx.y : (int)blockIdx.x) * 128;
  f32x4 acc[4][4] = {};
  gemm_core(A, B, DD, bm, bn, As, acc);

  const int lane = threadIdx.x & 63, wave = threadIdx.x >> 6;
  const int quad = lane >> 4, l16 = lane & 15;
  const int wm = (wave >> 1) * 64, wn = (wave & 1) * 64;
#pragma unroll
  for (int mt = 0; mt < 4; ++mt)
#pragma unroll
    for (int nt = 0; nt < 4; ++nt)
#pragma unroll
      for (int i = 0; i < 4; ++i) {
        int m = bm + wm + mt * 16 + quad * 4 + i;
        int n = bn + wn + nt * 16 + l16;
        float val = acc[mt][nt][i];
        if (z < 2) {  // head-split [B,H,L,DH]
          int b = m >> 11, l = m & 2047;
          C[((size_t)(b * HH + (n >> 6)) << 17) + (size_t)l * DHD + (n & 63)] = f2bf(val);
        } else {      // V^T [B,H,DH,L]
          int b = n >> 11, l = n & 2047;
          C[((size_t)(b * DD + m) << 11) + l] = f2bf(val);
        }
      }
}

// output projection: fp32 out, grid (8, 64)
__global__ __launch_bounds__(256) void out_gemm(const short* __restrict__ A, const short* __restrict__ B,
                                                float* __restrict__ C) {
  __shared__ short As[2 * 128 * 64];
  const int bm = blockIdx.y * 128, bn = blockIdx.x * 128;
  f32x4 acc[4][4] = {};
  gemm_core(A, B, DD, bm, bn, As, acc);
  const int lane = threadIdx.x & 63, wave = threadIdx.x >> 6;
  const int quad = lane >> 4, l16 = lane & 15;
  const int wm = (wave >> 1) * 64, wn = (wave & 1) * 64;
#pragma unroll
  for (int mt = 0; mt < 4; ++mt)
#pragma unroll
    for (int nt = 0; nt < 4; ++nt)
#pragma unroll
      for (int i = 0; i < 4; ++i) {
        int m = bm + wm + mt * 16 + quad * 4 + i;
        int n = bn + wn + nt * 16 + l16;
        C[(size_t)m * DD + n] = acc[mt][nt][i];
      }
}

// ---------------- flash attention (R4-proven version, restored verbatim) -----
// S^T formulation, max-free base-2 softmax; K/V staged via global_load_lds.
__global__ __launch_bounds__(256, 4) void attn_kernel(const short* __restrict__ Qh,
                                                      const short* __restrict__ Kh,
                                                      const short* __restrict__ VT,
                                                      const float* __restrict__ maskadd,
                                                      short* __restrict__ AO) {
  __shared__ short Ks[64 * 64];
  __shared__ short Vs[64 * 64];
  __shared__ short Pb[8 * 16 * 64];  // [wave][u][16 q-rows][64 s], XOR-swizzled
  const int tid  = threadIdx.x;
  const int lane = tid & 63, wave = tid >> 6;
  const int wv   = __builtin_amdgcn_readfirstlane(wave);
  const int quad = lane >> 4, l16 = lane & 15;
  const int a7 = l16 & 7, q1 = quad >> 1, qlo = quad & 1;
  const int bh = blockIdx.y, b = bh >> 4;
  const int q0 = blockIdx.x * 128;

  const float* mrow = maskadd + b * LL;
  const short* Qb = Qh + (size_t)bh * LL * DHD;
  const short* Kb = Kh + (size_t)bh * LL * DHD;
  const short* Vb = VT + (size_t)bh * DHD * LL;

  s16x8 qf[2][2];
#pragma unroll
  for (int u = 0; u < 2; ++u)
#pragma unroll
    for (int c = 0; c < 2; ++c)
      qf[u][c] = *(const s16x8*)&Qb[(size_t)(q0 + wv * 32 + u * 16 + l16) * DHD + c * 32 + quad * 8];

  const short* kp[2]; const short* vp[2]; short* lk[2]; short* lv[2];
#pragma unroll
  for (int t = 0; t < 2; ++t) {
    int s = wv * 128 + t * 64 + lane;
    int r = s >> 3, gl = (s & 7) ^ (r & 7);
    kp[t] = Kb + (size_t)r * DHD + gl * 8;
    vp[t] = Vb + (size_t)r * LL + gl * 8;
    lk[t] = &Ks[(wv * 128 + t * 64) * 8];
    lv[t] = &Vs[(wv * 128 + t * 64) * 8];
  }
  const int sw0 = (quad ^ a7) * 8;
  const int sw1 = ((4 + quad) ^ a7) * 8;

  s16x8 vone;
#pragma unroll
  for (int j = 0; j < 8; ++j) vone[j] = (short)0x3F80;  // bf16 1.0

  f32x4 lsum[2] = {};
  f32x4 accO[2][4] = {};
  short* pb = &Pb[wave * 2048 + l16 * 64 + qlo * 4];

  for (int s0 = 0; s0 < LL; s0 += 64) {
    f32x4 mm[4];
#pragma unroll
    for (int st = 0; st < 4; ++st) mm[st] = *(const f32x4*)&mrow[s0 + st * 16 + quad * 4];
    __syncthreads();
#pragma unroll
    for (int t = 0; t < 2; ++t) gl2lds16(kp[t] + (size_t)s0 * DHD, lk[t]);
#pragma unroll
    for (int t = 0; t < 2; ++t) gl2lds16(vp[t] + s0, lv[t]);
    __syncthreads();

    s16x8 kf[4][2];
#pragma unroll
    for (int st = 0; st < 4; ++st) {
      kf[st][0] = *(const s16x8*)&Ks[(st * 16 + l16) * 64 + sw0];
      kf[st][1] = *(const s16x8*)&Ks[(st * 16 + l16) * 64 + sw1];
    }
    f32x4 sc[2][4];
#pragma unroll
    for (int u = 0; u < 2; ++u)
#pragma unroll
      for (int st = 0; st < 4; ++st) {
        sc[u][st] = __builtin_amdgcn_mfma_f32_16x16x32_bf16(kf[st][0], qf[u][0], mm[st], 0, 0, 0);
        sc[u][st] = __builtin_amdgcn_mfma_f32_16x16x32_bf16(kf[st][1], qf[u][1], sc[u][st], 0, 0, 0);
      }

    // P = exp2(score); pack to bf16; write to Pb (A-operand layout transform)
#pragma unroll
    for (int u = 0; u < 2; ++u)
#pragma unroll
      for (int st = 0; st < 4; ++st) {
        float p0 = __builtin_amdgcn_exp2f(sc[u][st][0]);
        float p1 = __builtin_amdgcn_exp2f(sc[u][st][1]);
        float p2 = __builtin_amdgcn_exp2f(sc[u][st][2]);
        float p3 = __builtin_amdgcn_exp2f(sc[u][st][3]);
        u32x2 w; w[0] = pack2bf(p0, p1); w[1] = pack2bf(p2, p3);
        *(u32x2*)(pb + u * 1024 + (((st * 2 + q1) ^ a7) << 3)) = w;
      }

    s16x8 pf[2][2];
#pragma unroll
    for (int u = 0; u < 2; ++u)
#pragma unroll
      for (int c = 0; c < 2; ++c)
        pf[u][c] = *(const s16x8*)&Pb[(wave * 2 + u) * 1024 + l16 * 64 + (((c * 4 + quad) ^ a7) << 3)];
#pragma unroll
    for (int u = 0; u < 2; ++u) {
      lsum[u] = __builtin_amdgcn_mfma_f32_16x16x32_bf16(pf[u][0], vone, lsum[u], 0, 0, 0);
      lsum[u] = __builtin_amdgcn_mfma_f32_16x16x32_bf16(pf[u][1], vone, lsum[u], 0, 0, 0);
    }
#pragma unroll
    for (int dt = 0; dt < 4; ++dt) {
      s16x8 vf0 = *(const s16x8*)&Vs[(dt * 16 + l16) * 64 + sw0];
      s16x8 vf1 = *(const s16x8*)&Vs[(dt * 16 + l16) * 64 + sw1];
#pragma unroll
      for (int u = 0; u < 2; ++u) {
        accO[u][dt] = __builtin_amdgcn_mfma_f32_16x16x32_bf16(pf[u][0], vf0, accO[u][dt], 0, 0, 0);
        accO[u][dt] = __builtin_amdgcn_mfma_f32_16x16x32_bf16(pf[u][1], vf1, accO[u][dt], 0, 0, 0);
      }
    }
  }

  short* AOb = AO + (size_t)b * LL * DD + (size_t)(bh & 15) * DHD;
#pragma unroll
  for (int u = 0; u < 2; ++u) {
    f32x4 rl;
#pragma unroll
    for (int i = 0; i < 4; ++i) rl[i] = __builtin_amdgcn_rcpf(lsum[u][i]);
#pragma unroll
    for (int dt = 0; dt < 4; ++dt)
#pragma unroll
      for (int i = 0; i < 4; ++i) {
        int qr = q0 + wv * 32 + u * 16 + quad * 4 + i;
        AOb[(size_t)qr * DD + dt * 16 + l16] = f2bf(accO[u][dt][i] * rl[i]);
      }
  }
}

extern "C" void kernel_launch(void* const* d_in, const int* in_sizes, int n_in,
                              void* d_out, int out_size, void* d_ws, size_t ws_size,
                              hipStream_t stream) {
  const float* q   = (const float*)d_in[0];
  const float* k   = (const float*)d_in[1];
  const float* v   = (const float*)d_in[2];
  const int*  mask = (const int*)d_in[3];
  const float* Wq  = (const float*)d_in[4];
  const float* Wk  = (const float*)d_in[5];
  const float* Wv  = (const float*)d_in[6];
  const float* Wo  = (const float*)d_in[7];

  const size_t SX = (size_t)BB * LL * DD;  // 8,388,608
  const size_t SW = (size_t)DD * DD;       // 1,048,576
  short* w = (short*)d_ws;
  short* qb  = w;        short* kb  = qb + SX;  short* vb  = kb + SX;
  short* Wqb = vb + SX;  short* Wkb = Wqb + SW; short* Wvb = Wkb + SW; short* Wob = Wvb + SW;
  short* Qh  = Wob + SW; short* Kh  = Qh + SX;  short* VT  = Kh + SX;
  float* maskadd = (float*)(VT + SX);
  short* AO = qb;  // qb dead after QKV projections

  cast_x_kernel<<<dim3((unsigned)(SX / 4 / 256), 3), 256, 0, stream>>>(q, k, v, qb, kb, vb);
  cast_w_kernel<<<dim3((unsigned)(SW / 4 / 256), 4), 256, 0, stream>>>(Wq, Wk, Wv, Wo, Wqb, Wkb, Wvb, Wob);
  mask_kernel<<<BB * LL / 4 / 256, 256, 0, stream>>>(mask, maskadd);

  qkv_gemm<<<dim3(8, 64, 3), 256, 0, stream>>>(qb, kb, vb, Wqb, Wkb, Wvb, Qh, Kh, VT);
  attn_kernel<<<dim3(LL / 128, BB * HH), 256, 0, stream>>>(Qh, Kh, VT, maskadd, AO);
  out_gemm<<<dim3(8, 64), 256, 0, stream>>>(AO, Wob, (float*)d_out);
}